// Round 2
// baseline (1382.081 us; speedup 1.0000x reference)
//
#include <hip/hip_runtime.h>
#include <hip/hip_bf16.h>

#define D 64
#define HID 36
#define IN_DIM 192

// ---------------------------------------------------------------------------
// generic zero kernel (16B granules)
// ---------------------------------------------------------------------------
__global__ void zero_ws_kernel(float4* __restrict__ p, long n4) {
    long i = (long)blockIdx.x * blockDim.x + threadIdx.x;
    long stride = (long)gridDim.x * blockDim.x;
    float4 z = make_float4(0.f, 0.f, 0.f, 0.f);
    for (; i < n4; i += stride) p[i] = z;
}

// ---------------------------------------------------------------------------
// FALLBACK path (ws too small): atomic scatter (R0 version)
// ---------------------------------------------------------------------------
__global__ __launch_bounds__(256) void scatter_kernel(
    const float* __restrict__ edges,
    const int* __restrict__ senders,
    const int* __restrict__ receivers,
    float* __restrict__ sent,
    float* __restrict__ recv,
    long total)
{
    long i = (long)blockIdx.x * blockDim.x + threadIdx.x;
    if (i >= total) return;
    long e = i >> 6;
    int  d = (int)(i & 63);
    float v = edges[i];
    int s = senders[e];
    int r = receivers[e];
    unsafeAtomicAdd(&sent[(long)s * D + d], v);
    unsafeAtomicAdd(&recv[(long)r * D + d], v);
}

// ---------------------------------------------------------------------------
// CSR build: histogram -> 3-kernel exclusive scan -> fill
// counts/offsets/cursor are [2*n_nodes]: sent lists first, recv lists second.
// ---------------------------------------------------------------------------
__global__ __launch_bounds__(256) void hist_kernel(
    const int* __restrict__ senders,
    const int* __restrict__ receivers,
    int* __restrict__ counts,   // [2*n_nodes], pre-zeroed
    int n_nodes, long n_edges)
{
    long i = (long)blockIdx.x * blockDim.x + threadIdx.x;
    if (i >= n_edges) return;
    atomicAdd(&counts[senders[i]], 1);
    atomicAdd(&counts[n_nodes + receivers[i]], 1);
}

__global__ __launch_bounds__(1024) void scan1_kernel(
    const int* __restrict__ counts,
    int* __restrict__ pre,      // exclusive within block
    int* __restrict__ bsums,
    int n)
{
    __shared__ int tmp[1024];
    int tid = threadIdx.x;
    int g = blockIdx.x * 1024 + tid;
    int v = (g < n) ? counts[g] : 0;
    tmp[tid] = v;
    __syncthreads();
    for (int off = 1; off < 1024; off <<= 1) {
        int t = (tid >= off) ? tmp[tid - off] : 0;
        __syncthreads();
        tmp[tid] += t;
        __syncthreads();
    }
    if (g < n) pre[g] = tmp[tid] - v;
    if (tid == 1023) bsums[blockIdx.x] = tmp[1023];
}

__global__ __launch_bounds__(256) void scan2_kernel(int* __restrict__ bsums, int nb)
{
    __shared__ int tmp[256];
    int tid = threadIdx.x;
    int v = (tid < nb) ? bsums[tid] : 0;
    tmp[tid] = v;
    __syncthreads();
    for (int off = 1; off < 256; off <<= 1) {
        int t = (tid >= off) ? tmp[tid - off] : 0;
        __syncthreads();
        tmp[tid] += t;
        __syncthreads();
    }
    if (tid < nb) bsums[tid] = tmp[tid] - v;   // exclusive block base
}

__global__ __launch_bounds__(256) void scan3_kernel(
    const int* __restrict__ pre,
    const int* __restrict__ bsums,
    int* __restrict__ offsets,
    int* __restrict__ cursor,
    int n)
{
    int g = blockIdx.x * blockDim.x + threadIdx.x;
    if (g >= n) return;
    int o = pre[g] + bsums[g >> 10];
    offsets[g] = o;
    cursor[g]  = o;
}

__global__ __launch_bounds__(256) void fill_kernel(
    const int* __restrict__ senders,
    const int* __restrict__ receivers,
    int* __restrict__ cursor,
    int* __restrict__ pool,     // [2*n_edges] edge ids
    int n_nodes, long n_edges)
{
    long i = (long)blockIdx.x * blockDim.x + threadIdx.x;
    if (i >= n_edges) return;
    int s = senders[i];
    int p = atomicAdd(&cursor[s], 1);
    pool[p] = (int)i;
    int r = receivers[i];
    int p2 = atomicAdd(&cursor[n_nodes + r], 1);
    pool[p2] = (int)i;
}

// ---------------------------------------------------------------------------
// Gather: one wave (64 lanes) per node. Each list iteration reads one full
// edge row: edges[e*64 + lane] -> 256B coalesced. lane == feature index.
// ---------------------------------------------------------------------------
__global__ __launch_bounds__(256) void gather_kernel(
    const float* __restrict__ edges,
    const int* __restrict__ pool,
    const int* __restrict__ offsets,  // start
    const int* __restrict__ cursor,   // end (== start + count after fill)
    float* __restrict__ sent,
    float* __restrict__ recv,
    int n_nodes)
{
    int gtid = blockIdx.x * blockDim.x + threadIdx.x;
    int node = gtid >> 6;
    int lane = gtid & 63;
    if (node >= n_nodes) return;

    int s0 = offsets[node],           s1 = cursor[node];
    int r0 = offsets[n_nodes + node], r1 = cursor[n_nodes + node];

    float accs = 0.f;
    int i = s0;
    for (; i + 2 <= s1; i += 2) {
        int e0 = pool[i], e1 = pool[i + 1];
        float v0 = edges[(long)e0 * D + lane];
        float v1 = edges[(long)e1 * D + lane];
        accs += v0 + v1;
    }
    if (i < s1) accs += edges[(long)pool[i] * D + lane];

    float accr = 0.f;
    i = r0;
    for (; i + 2 <= r1; i += 2) {
        int e0 = pool[i], e1 = pool[i + 1];
        float v0 = edges[(long)e0 * D + lane];
        float v1 = edges[(long)e1 * D + lane];
        accr += v0 + v1;
    }
    if (i < r1) accr += edges[(long)pool[i] * D + lane];

    sent[(long)node * D + lane] = accs;
    recv[(long)node * D + lane] = accr;
}

// ---------------------------------------------------------------------------
// per-node MLP (unchanged from R0)
// ---------------------------------------------------------------------------
__global__ __launch_bounds__(256) void mlp_kernel(
    const float* __restrict__ nodes,
    const float* __restrict__ sent,
    const float* __restrict__ recv,
    const float* __restrict__ W1,
    const float* __restrict__ b1,
    const float* __restrict__ W2,
    const float* __restrict__ b2,
    float* __restrict__ out,
    int n)
{
    __shared__ float sW1[IN_DIM * HID];
    __shared__ float sb1[HID];
    __shared__ float sW2[HID * 2];
    __shared__ float sb2[2];

    for (int t = threadIdx.x; t < IN_DIM * HID; t += blockDim.x) sW1[t] = W1[t];
    if (threadIdx.x < HID)     sb1[threadIdx.x] = b1[threadIdx.x];
    if (threadIdx.x < HID * 2) sW2[threadIdx.x] = W2[threadIdx.x];
    if (threadIdx.x < 2)       sb2[threadIdx.x] = b2[threadIdx.x];
    __syncthreads();

    int node = blockIdx.x * blockDim.x + threadIdx.x;
    if (node >= n) return;

    float acc[HID];
#pragma unroll
    for (int j = 0; j < HID; ++j) acc[j] = sb1[j];

#pragma unroll
    for (int part = 0; part < 3; ++part) {
        const float* f = (part == 0 ? nodes : (part == 1 ? sent : recv)) + (long)node * D;
        const float* w = sW1 + part * D * HID;
        for (int k = 0; k < D; k += 4) {
            float4 fv = *reinterpret_cast<const float4*>(f + k);
#pragma unroll
            for (int j = 0; j < HID; ++j) {
                acc[j] += fv.x * w[(k + 0) * HID + j];
                acc[j] += fv.y * w[(k + 1) * HID + j];
                acc[j] += fv.z * w[(k + 2) * HID + j];
                acc[j] += fv.w * w[(k + 3) * HID + j];
            }
        }
    }

    float o0 = sb2[0], o1 = sb2[1];
#pragma unroll
    for (int j = 0; j < HID; ++j) {
        float h = fmaxf(acc[j], 0.f);
        o0 += h * sW2[j * 2 + 0];
        o1 += h * sW2[j * 2 + 1];
    }
    reinterpret_cast<float2*>(out)[node] = make_float2(o0, o1);
}

// ---------------------------------------------------------------------------
extern "C" void kernel_launch(void* const* d_in, const int* in_sizes, int n_in,
                              void* d_out, int out_size, void* d_ws, size_t ws_size,
                              hipStream_t stream) {
    const float* nodes     = (const float*)d_in[0];
    const float* edges     = (const float*)d_in[1];
    const int*   senders   = (const int*)d_in[2];
    const int*   receivers = (const int*)d_in[3];
    const float* W1        = (const float*)d_in[4];
    const float* b1        = (const float*)d_in[5];
    const float* W2        = (const float*)d_in[6];
    const float* b2        = (const float*)d_in[7];
    float* out = (float*)d_out;

    const int  n_nodes = in_sizes[0] / D;     // 100,000
    const long n_edges = in_sizes[2];         // 3,200,000

    // ws layout
    const size_t sz_sent  = (size_t)n_nodes * D * sizeof(float);       // 25.6 MB
    const size_t sz_recv  = sz_sent;                                   // 25.6 MB
    const size_t sz_pool  = (size_t)2 * n_edges * sizeof(int);         // 25.6 MB
    const size_t sz_cnt   = (size_t)2 * n_nodes * sizeof(int);         // 0.8 MB
    const size_t need = sz_sent + sz_recv + sz_pool + 3 * sz_cnt + 4096;

    char* wp = (char*)d_ws;
    float* sent    = (float*)wp;            wp += sz_sent;
    float* recv    = (float*)wp;            wp += sz_recv;
    int*   pool    = (int*)wp;              wp += sz_pool;
    int*   counts  = (int*)wp;              wp += sz_cnt;
    int*   offsets = (int*)wp;              wp += sz_cnt;
    int*   cursor  = (int*)wp;              wp += sz_cnt;
    int*   bsums   = (int*)wp;

    if (ws_size < need) {
        // FALLBACK: R0 atomic-scatter path (needs only sent+recv = 51.2 MB)
        long n4 = (long)n_nodes * D * 2 / 4;
        zero_ws_kernel<<<2048, 256, 0, stream>>>((float4*)d_ws, n4);
        long total = n_edges * D;
        long blocks = (total + 255) / 256;
        scatter_kernel<<<(int)blocks, 256, 0, stream>>>(edges, senders, receivers,
                                                        sent, recv, total);
        int mblocks = (n_nodes + 255) / 256;
        mlp_kernel<<<mblocks, 256, 0, stream>>>(nodes, sent, recv,
                                                W1, b1, W2, b2, out, n_nodes);
        return;
    }

    const int n2 = 2 * n_nodes;              // 200,000 count slots

    // 1) zero counts
    {
        long n4 = sz_cnt / 16;
        zero_ws_kernel<<<64, 256, 0, stream>>>((float4*)counts, n4);
    }
    // 2) histogram
    {
        long blocks = (n_edges + 255) / 256;
        hist_kernel<<<(int)blocks, 256, 0, stream>>>(senders, receivers, counts,
                                                     n_nodes, n_edges);
    }
    // 3) scan
    {
        int nb = (n2 + 1023) / 1024;         // 196
        scan1_kernel<<<nb, 1024, 0, stream>>>(counts, offsets /*pre*/, bsums, n2);
        scan2_kernel<<<1, 256, 0, stream>>>(bsums, nb);
        int b3 = (n2 + 255) / 256;
        // note: scan3 reads offsets (pre) and rewrites offsets in place + cursor
        scan3_kernel<<<b3, 256, 0, stream>>>(offsets, bsums, offsets, cursor, n2);
    }
    // 4) fill CSR pool
    {
        long blocks = (n_edges + 255) / 256;
        fill_kernel<<<(int)blocks, 256, 0, stream>>>(senders, receivers, cursor,
                                                     pool, n_nodes, n_edges);
    }
    // 5) gather (one wave per node)
    {
        int waves_per_block = 4;             // 256 threads
        int blocks = (n_nodes + waves_per_block - 1) / waves_per_block;
        gather_kernel<<<blocks, 256, 0, stream>>>(edges, pool, offsets, cursor,
                                                  sent, recv, n_nodes);
    }
    // 6) MLP
    {
        int blocks = (n_nodes + 255) / 256;
        mlp_kernel<<<blocks, 256, 0, stream>>>(nodes, sent, recv,
                                               W1, b1, W2, b2, out, n_nodes);
    }
}